// Round 1
// baseline (413.408 us; speedup 1.0000x reference)
//
#include <hip/hip_runtime.h>

// Piecewise-linear sigmoid LUT, 65 points uniform on [-8, 8].
// out = in_range(x) ? a[seg]*x + b[seg] : 0;  out += (x >= xs[63]) ? 1 : 0
// seg = clamp(floor((x - xs[0]) * 4), 0, 63)
//
// Key change vs prior version: NSEG == wavefront size (64), so the (a,b) table
// lives in LANE REGISTERS (lane l holds a[l], b[l]) and the data-dependent
// gather is two ds_bpermute (__shfl) ops — crossbar, no LDS bank conflicts —
// instead of a ds_read_b64 into a 16-bank-pair-folded LDS table.
// Also: exact-cover fully-unrolled 8x float4 per thread, nontemporal ld/st
// (512 MiB streamed; input alone fills the 256 MiB L3 — don't pollute it).

#define NSEG 64

typedef float v4f __attribute__((ext_vector_type(4)));

__device__ __forceinline__ void lut_init(const float* __restrict__ table,
                                         float& a_reg, float& b_reg,
                                         float& x_lo, float& x_hi, float& x_last)
{
    const int lane = threadIdx.x & 63;
    // lane l: segment l endpoints (rows l and l+1 of the (65,2) table)
    float xs0 = table[2 * lane + 0];
    float ys0 = table[2 * lane + 1];
    float xs1 = table[2 * lane + 2];
    float ys1 = table[2 * lane + 3];
    a_reg = (ys1 - ys0) / (xs1 - xs0);
    b_reg = ys0 - a_reg * xs0;
    x_lo   = table[0];        // xs[0]  = -8
    x_hi   = table[2 * 64];   // xs[64] =  8
    x_last = table[2 * 63];   // xs[63] =  7.75
}

__device__ __forceinline__ float pwl_one(float xv, float a_reg, float b_reg,
                                         float x_lo, float x_hi, float x_last)
{
    // identical rounding path to the previously-verified kernel
    float segf = fminf(fmaxf((xv - x_lo) * 4.0f, 0.0f), 63.0f);
    int seg = (int)segf;
    float a = __shfl(a_reg, seg, 64);   // ds_bpermute_b32 — conflict-free
    float b = __shfl(b_reg, seg, 64);
    float f = fmaf(a, xv, b);
    f = ((xv >= x_lo) && (xv < x_hi)) ? f : 0.0f;
    f += (xv >= x_last) ? 1.0f : 0.0f;
    return f;
}

// Exact-cover kernel: grid chosen so blocks * 256 threads * ITERS == n4.
// Each block owns a contiguous 256*ITERS float4 chunk; iteration k is a
// coalesced, independent 16B nt-load -> compute -> 16B nt-store.
template<int ITERS>
__global__ __launch_bounds__(256) void pwl_sigmoid_exact(
    const float* __restrict__ x,
    const float* __restrict__ table,
    float* __restrict__ out)
{
    float a_reg, b_reg, x_lo, x_hi, x_last;
    lut_init(table, a_reg, b_reg, x_lo, x_hi, x_last);

    const int t    = threadIdx.x;
    const int base = blockIdx.x * (256 * ITERS) + t;
    const v4f* __restrict__ xin = reinterpret_cast<const v4f*>(x);
    v4f* __restrict__ o         = reinterpret_cast<v4f*>(out);

    v4f v[ITERS];                 // fully unrolled -> static indices -> VGPRs
#pragma unroll
    for (int k = 0; k < ITERS; ++k)
        v[k] = __builtin_nontemporal_load(xin + (base + k * 256));

#pragma unroll
    for (int k = 0; k < ITERS; ++k) {
        v4f r;
#pragma unroll
        for (int j = 0; j < 4; ++j)
            r[j] = pwl_one(v[k][j], a_reg, b_reg, x_lo, x_hi, x_last);
        __builtin_nontemporal_store(r, o + (base + k * 256));
    }
}

// Fallback: grid-stride (same math), for shapes the exact kernel doesn't cover.
__global__ __launch_bounds__(256) void pwl_sigmoid_stride(
    const float* __restrict__ x,
    const float* __restrict__ table,
    float* __restrict__ out,
    int n4)
{
    float a_reg, b_reg, x_lo, x_hi, x_last;
    lut_init(table, a_reg, b_reg, x_lo, x_hi, x_last);

    const v4f* __restrict__ xin = reinterpret_cast<const v4f*>(x);
    v4f* __restrict__ o         = reinterpret_cast<v4f*>(out);

    const int stride = gridDim.x * blockDim.x;
    for (int i = blockIdx.x * blockDim.x + threadIdx.x; i < n4; i += stride) {
        v4f v = __builtin_nontemporal_load(xin + i);
        v4f r;
#pragma unroll
        for (int j = 0; j < 4; ++j)
            r[j] = pwl_one(v[j], a_reg, b_reg, x_lo, x_hi, x_last);
        __builtin_nontemporal_store(r, o + i);
    }
}

extern "C" void kernel_launch(void* const* d_in, const int* in_sizes, int n_in,
                              void* d_out, int out_size, void* d_ws, size_t ws_size,
                              hipStream_t stream) {
    const float* x     = (const float*)d_in[0];
    const float* table = (const float*)d_in[1];
    float* out = (float*)d_out;

    int n  = in_sizes[0];          // 8*4096*2048 = 67108864, divisible by 4
    int n4 = n / 4;

    constexpr int ITERS  = 8;      // 8 independent float4 (128 B) in flight/thread
    const int threads    = 256;

    if ((n % 4) == 0 && (n4 % (threads * ITERS)) == 0) {
        int blocks = n4 / (threads * ITERS);   // 8192 for this problem
        pwl_sigmoid_exact<ITERS><<<blocks, threads, 0, stream>>>(x, table, out);
    } else {
        int blocks = 8192;
        pwl_sigmoid_stride<<<blocks, threads, 0, stream>>>(x, table, out, n4);
    }
}